// Round 3
// baseline (1109.029 us; speedup 1.0000x reference)
//
#include <hip/hip_runtime.h>
#include <math.h>

// ---------------- problem constants ----------------
#define DD   128
#define MM   4096
#define NSTEP 4
#define NEG_INF (-3.4e38f)

// ---------------- ws float-offset layout ----------------
#define WS_H    0          // 128
#define WS_C    128        // 128
#define WS_GS   512        // 4: [gs0,gs1,ge0,ge1]
#define WS_RT   1024       // 4096: [suf][k*1024+e]
#define WS_Z0   8192       // f32 z0 [suf*2+k][4096][1024] = 16,777,216 floats
#define WS_END  (8192 + 16777216)   // 16,785,408 floats = 67,141,632 B

typedef __attribute__((ext_vector_type(8))) short bf16x8;
typedef __attribute__((ext_vector_type(4))) float f32x4;
typedef __attribute__((ext_vector_type(4))) unsigned short u16x4;

static __device__ __forceinline__ unsigned short f2b(float x) {
  unsigned u = __float_as_uint(x);
  unsigned r = (u + 0x7fffu + ((u >> 16) & 1u)) >> 16;   // RNE
  return (unsigned short)r;
}
static __device__ __forceinline__ float b2f(unsigned short h) {
  return __uint_as_float(((unsigned)h) << 16);
}
static __device__ __forceinline__ void split4(float4 v, u16x4* h, u16x4* l) {
  unsigned short h0 = f2b(v.x), h1 = f2b(v.y), h2 = f2b(v.z), h3 = f2b(v.w);
  u16x4 hh = {h0, h1, h2, h3};
  u16x4 ll = {f2b(v.x - b2f(h0)), f2b(v.y - b2f(h1)),
              f2b(v.z - b2f(h2)), f2b(v.w - b2f(h3))};
  *h = hh; *l = ll;
}

// =====================================================================
// init: reset h, c each launch (graph replays)
// =====================================================================
__global__ void k_init(float* __restrict__ ws) {
  int t = threadIdx.x;
  if (t < 128) { ws[WS_H + t] = 0.f; ws[WS_C + t] = 0.f; }
}

// =====================================================================
// Z0 split-bf16 MFMA GEMM (f32-grade):
// z0[z][m][e] = sum_{f<256} U[m][f] * We_z[e][f],  z = suf*2+k
// grid (32, 8, 4), 256 thr = 4 waves (2x2 of 64x64), BK=32, on-the-fly split
// =====================================================================
__global__ __launch_bounds__(256) void k_z0m(
    const float* __restrict__ U,
    const float* __restrict__ We_s, const float* __restrict__ We_e,
    float* __restrict__ ws) {
  __shared__ unsigned short Ah[128][40];
  __shared__ unsigned short Al[128][40];
  __shared__ unsigned short Bh[128][40];
  __shared__ unsigned short Bl[128][40];
  float* z0 = ws + WS_Z0;

  int t = threadIdx.x;
  int lane = t & 63, wid = t >> 6;
  int wm = wid >> 1, wn = wid & 1;
  int lr = lane & 15, lk = (lane >> 4) * 8, lq = lane >> 4;
  int m0 = blockIdx.x * 128, e0 = blockIdx.y * 128;
  int z = blockIdx.z;
  int suf = z >> 1, k = z & 1;
  const float* Wep = (suf ? We_e : We_s) + (size_t)k * 1024 * 384;

  f32x4 acc[4][4];
  f32x4 zz = {0.f, 0.f, 0.f, 0.f};
#pragma unroll
  for (int i = 0; i < 4; ++i)
#pragma unroll
    for (int n = 0; n < 4; ++n) acc[i][n] = zz;

  for (int kc = 0; kc < 8; ++kc) {
    int k0 = kc * 32;
    __syncthreads();
#pragma unroll
    for (int it = 0; it < 4; ++it) {
      int idx = t + it * 256;           // 1024 float4 per operand tile
      int row = idx >> 3, q = idx & 7;
      float4 va = *(const float4*)&U[(size_t)(m0 + row) * 256 + k0 + q * 4];
      u16x4 h, l; split4(va, &h, &l);
      *(u16x4*)&Ah[row][q * 4] = h;
      *(u16x4*)&Al[row][q * 4] = l;
      float4 vb = *(const float4*)&Wep[(size_t)(e0 + row) * 384 + k0 + q * 4];
      split4(vb, &h, &l);
      *(u16x4*)&Bh[row][q * 4] = h;
      *(u16x4*)&Bl[row][q * 4] = l;
    }
    __syncthreads();
    bf16x8 ah[4], al[4], bh[4], bl[4];
#pragma unroll
    for (int i = 0; i < 4; ++i) {
      ah[i] = *(bf16x8*)&Ah[wm * 64 + i * 16 + lr][lk];
      al[i] = *(bf16x8*)&Al[wm * 64 + i * 16 + lr][lk];
    }
#pragma unroll
    for (int n = 0; n < 4; ++n) {
      bh[n] = *(bf16x8*)&Bh[wn * 64 + n * 16 + lr][lk];
      bl[n] = *(bf16x8*)&Bl[wn * 64 + n * 16 + lr][lk];
    }
#pragma unroll
    for (int i = 0; i < 4; ++i)
#pragma unroll
      for (int n = 0; n < 4; ++n) {
        acc[i][n] = __builtin_amdgcn_mfma_f32_16x16x32_bf16(ah[i], bh[n], acc[i][n], 0, 0, 0);
        acc[i][n] = __builtin_amdgcn_mfma_f32_16x16x32_bf16(ah[i], bl[n], acc[i][n], 0, 0, 0);
        acc[i][n] = __builtin_amdgcn_mfma_f32_16x16x32_bf16(al[i], bh[n], acc[i][n], 0, 0, 0);
      }
  }

  float* C = z0 + (size_t)z * MM * 1024;
#pragma unroll
  for (int i = 0; i < 4; ++i)
#pragma unroll
    for (int n = 0; n < 4; ++n)
#pragma unroll
      for (int r = 0; r < 4; ++r) {
        int row = m0 + wm * 64 + i * 16 + lq * 4 + r;
        int col = e0 + wn * 64 + n * 16 + lr;
        C[(size_t)row * 1024 + col] = acc[i][n][r];
      }
}

// =====================================================================
// state (fused): argmax(prev) -> si/ei, LSTM, r_s/r_e, gates, rterm.
// 1 block, 512 threads. All f32.
// =====================================================================
__global__ void k_state(
    const float* __restrict__ U,
    const float* __restrict__ Wih, const float* __restrict__ Whh,
    const float* __restrict__ bih, const float* __restrict__ bhh,
    const float* __restrict__ Wr_s, const float* __restrict__ br_s,
    const float* __restrict__ Wg_s, const float* __restrict__ bg_s,
    const float* __restrict__ We_s, const float* __restrict__ be_s,
    const float* __restrict__ Wr_e, const float* __restrict__ br_e,
    const float* __restrict__ Wg_e, const float* __restrict__ bg_e,
    const float* __restrict__ We_e, const float* __restrict__ be_e,
    const float* __restrict__ out, int step,
    float* __restrict__ ws) {
  __shared__ float red_v[512];
  __shared__ int   red_i[512];
  __shared__ int   si_sh, ei_sh;
  __shared__ float xs[512];
  __shared__ float hs[128];
  __shared__ float gsh[512];
  __shared__ float ctx[640];
  __shared__ float rsh[128], reh[128];
  __shared__ float logit[4];
  int t = threadIdx.x;

  // ---- argmax of previous step's scores (first-max index) ----
  if (step > 0) {
    int half = t >> 8, l = t & 255;
    const float* arr = out + (size_t)half * (NSTEP * MM) + (size_t)(step - 1) * MM;
    float bv = NEG_INF; int bi = 0;
    for (int i = l; i < MM; i += 256) {
      float v = arr[i];
      if (v > bv) { bv = v; bi = i; }
    }
    red_v[t] = bv; red_i[t] = bi;
    __syncthreads();
    for (int s = 128; s > 0; s >>= 1) {
      if (l < s) {
        float v2 = red_v[t + s]; int i2 = red_i[t + s];
        if (v2 > red_v[t] || (v2 == red_v[t] && i2 < red_i[t])) { red_v[t] = v2; red_i[t] = i2; }
      }
      __syncthreads();
    }
    if (t == 0)   si_sh = red_i[0];
    if (t == 256) ei_sh = red_i[256];
  } else {
    if (t == 0) { si_sh = 0; ei_sh = MM - 1; }
  }
  __syncthreads();
  int si = si_sh, ei = ei_sh;

  if (t < 256) xs[t] = U[(size_t)si * 256 + t];
  else         xs[t] = U[(size_t)ei * 256 + (t - 256)];
  if (t < 128) hs[t] = ws[WS_H + t];
  __syncthreads();

  // ---- LSTM gates ----
  {
    float acc = bih[t] + bhh[t];
    const float* wr = Wih + (size_t)t * 512;
    for (int j = 0; j < 512; j += 4) {
      float4 w = *(const float4*)&wr[j];
      acc += w.x * xs[j] + w.y * xs[j + 1] + w.z * xs[j + 2] + w.w * xs[j + 3];
    }
    const float* wh = Whh + (size_t)t * 128;
    for (int j = 0; j < 128; j += 4) {
      float4 w = *(const float4*)&wh[j];
      acc += w.x * hs[j] + w.y * hs[j + 1] + w.z * hs[j + 2] + w.w * hs[j + 3];
    }
    gsh[t] = acc;
  }
  __syncthreads();
  if (t < 128) {
    float ig = 1.f / (1.f + expf(-gsh[t]));
    float fg = 1.f / (1.f + expf(-gsh[128 + t]));
    float gg = tanhf(gsh[256 + t]);
    float og = 1.f / (1.f + expf(-gsh[384 + t]));
    float c2 = fg * ws[WS_C + t] + ig * gg;
    float h2 = og * tanhf(c2);
    ws[WS_C + t] = c2;
    ws[WS_H + t] = h2;
    ctx[t] = h2;
  }
  ctx[128 + t] = xs[t];
  __syncthreads();

  // ---- r_s, r_e, gate logits ----
  if (t < 128) {
    float acc = br_s[t];
    const float* w = Wr_s + (size_t)t * 640;
    for (int j = 0; j < 640; j += 4) {
      float4 wv = *(const float4*)&w[j];
      acc += wv.x * ctx[j] + wv.y * ctx[j + 1] + wv.z * ctx[j + 2] + wv.w * ctx[j + 3];
    }
    rsh[t] = tanhf(acc);
  } else if (t < 256) {
    int i = t - 128;
    float acc = br_e[i];
    const float* w = Wr_e + (size_t)i * 640;
    for (int j = 0; j < 640; j += 4) {
      float4 wv = *(const float4*)&w[j];
      acc += wv.x * ctx[j] + wv.y * ctx[j + 1] + wv.z * ctx[j + 2] + wv.w * ctx[j + 3];
    }
    reh[i] = tanhf(acc);
  } else if (t < 260) {
    int which = t - 256;
    const float* Wg = (which < 2) ? Wg_s : Wg_e;
    const float* bg = (which < 2) ? bg_s : bg_e;
    int i = which & 1;
    float acc = bg[i];
    const float* w = Wg + (size_t)i * 640;
    for (int j = 0; j < 640; j += 4) {
      float4 wv = *(const float4*)&w[j];
      acc += wv.x * ctx[j] + wv.y * ctx[j + 1] + wv.z * ctx[j + 2] + wv.w * ctx[j + 3];
    }
    logit[which] = acc;
  }
  __syncthreads();
  if (t == 0) {
    float a = logit[0], b = logit[1], mx = fmaxf(a, b);
    float ea = expf(a - mx), eb = expf(b - mx), s = ea + eb;
    ws[WS_GS + 0] = ea / s; ws[WS_GS + 1] = eb / s;
    a = logit[2]; b = logit[3]; mx = fmaxf(a, b);
    ea = expf(a - mx); eb = expf(b - mx); s = ea + eb;
    ws[WS_GS + 2] = ea / s; ws[WS_GS + 3] = eb / s;
  }

  // ---- rterm[suf][ke] = be[ke] + We_tail[ke] . r_suf ----
  for (int it = 0; it < 8; ++it) {
    int glob = t + it * 512;            // 0..4095
    int suf = glob >> 11, rest = glob & 2047;
    const float* We = suf ? We_e : We_s;
    const float* be = suf ? be_e : be_s;
    const float* r  = suf ? reh : rsh;
    const float* w  = We + (size_t)rest * 384 + 256;
    float acc = be[rest];
    for (int j = 0; j < 128; j += 4) {
      float4 wv = *(const float4*)&w[j];
      acc += wv.x * r[j] + wv.y * r[j + 1] + wv.z * r[j + 2] + wv.w * r[j + 3];
    }
    ws[WS_RT + glob] = acc;
  }
}

// =====================================================================
// score: ph1 f32 maxout+mix -> m1f; ph2 split-bf16 MFMA m1@W2^T maxout -> m2f;
// ph3 f32 [m1|m2]@W3^T max -> scores.  grid (128, 2), 256 thr.
// =====================================================================
__global__ __launch_bounds__(256) void k_score(
    const float* __restrict__ W2_a, const float* __restrict__ b2_a,
    const float* __restrict__ W3_a, const float* __restrict__ b3_a,
    const float* __restrict__ W2_b, const float* __restrict__ b2_b,
    const float* __restrict__ W3_b, const float* __restrict__ b3_b,
    float* __restrict__ out_a, float* __restrict__ out_b,
    float* __restrict__ ws) {
  __shared__ float rtm[2048];
  __shared__ float m1f[32][132];
  __shared__ unsigned short w2h[128][136];
  __shared__ unsigned short w2l[128][136];
  __shared__ float m2f[32][132];
  __shared__ float sj[32][8];

  const float* z0 = ws + WS_Z0;
  int t = threadIdx.x;
  int suf = blockIdx.y;
  int m0 = blockIdx.x * 32;
  const float* W2 = suf ? W2_b : W2_a;
  const float* b2 = suf ? b2_b : b2_a;
  const float* W3 = suf ? W3_b : W3_a;
  const float* b3 = suf ? b3_b : b3_a;
  float*     outp = suf ? out_b : out_a;
  float g0 = ws[WS_GS + suf * 2 + 0];
  float g1 = ws[WS_GS + suf * 2 + 1];

  for (int l = t; l < 2048; l += 256) rtm[l] = ws[WS_RT + suf * 2048 + l];
  __syncthreads();

  // ---- phase 1: f32 maxout over p, mixture over k -> m1f ----
  {
    int cg = t & 31, rgi = t >> 5;
    int c4 = cg * 4;
    const float* z00 = z0 + (size_t)(suf * 2 + 0) * MM * 1024;
    const float* z01 = z0 + (size_t)(suf * 2 + 1) * MM * 1024;
#pragma unroll
    for (int it = 0; it < 4; ++it) {
      int row = it * 8 + rgi;
      size_t mb = (size_t)(m0 + row) * 1024;
      float4 mx0 = {NEG_INF, NEG_INF, NEG_INF, NEG_INF};
      float4 mx1 = mx0;
#pragma unroll
      for (int pp = 0; pp < 8; ++pp) {
        float4 v0 = *(const float4*)&z00[mb + pp * 128 + c4];
        float4 r0 = *(const float4*)&rtm[pp * 128 + c4];
        mx0.x = fmaxf(mx0.x, v0.x + r0.x); mx0.y = fmaxf(mx0.y, v0.y + r0.y);
        mx0.z = fmaxf(mx0.z, v0.z + r0.z); mx0.w = fmaxf(mx0.w, v0.w + r0.w);
        float4 v1 = *(const float4*)&z01[mb + pp * 128 + c4];
        float4 r1 = *(const float4*)&rtm[1024 + pp * 128 + c4];
        mx1.x = fmaxf(mx1.x, v1.x + r1.x); mx1.y = fmaxf(mx1.y, v1.y + r1.y);
        mx1.z = fmaxf(mx1.z, v1.z + r1.z); mx1.w = fmaxf(mx1.w, v1.w + r1.w);
      }
      float4 m1v = {g0 * mx0.x + g1 * mx1.x, g0 * mx0.y + g1 * mx1.y,
                    g0 * mx0.z + g1 * mx1.z, g0 * mx0.w + g1 * mx1.w};
      *(float4*)&m1f[row][c4] = m1v;
    }
  }
  __syncthreads();

  // ---- per-wave A-fragments (split m1 to hi/lo in registers) ----
  int lane = t & 63, wid = t >> 6;
  int rh = wid & 1, cq = wid >> 1;
  int lr = lane & 15, lk = (lane >> 4) * 8, lq = lane >> 4;
  bf16x8 ah[4], al[4];
#pragma unroll
  for (int kk = 0; kk < 4; ++kk) {
    float4 x0 = *(const float4*)&m1f[rh * 16 + lr][kk * 32 + lk];
    float4 x1 = *(const float4*)&m1f[rh * 16 + lr][kk * 32 + lk + 4];
    u16x4 h0, l0, h1, l1;
    split4(x0, &h0, &l0); split4(x1, &h1, &l1);
    bf16x8 a, b;
#pragma unroll
    for (int j = 0; j < 4; ++j) { a[j] = (short)h0[j]; a[4 + j] = (short)h1[j]; }
#pragma unroll
    for (int j = 0; j < 4; ++j) { b[j] = (short)l0[j]; b[4 + j] = (short)l1[j]; }
    ah[kk] = a; al[kk] = b;
  }

  // ---- phase 2: split-bf16 MFMA, maxout over sp ----
  float m2x[4][4];
#pragma unroll
  for (int nt = 0; nt < 4; ++nt)
#pragma unroll
    for (int r = 0; r < 4; ++r) m2x[nt][r] = NEG_INF;

  for (int sp = 0; sp < 8; ++sp) {
    __syncthreads();
#pragma unroll
    for (int it = 0; it < 16; ++it) {
      int idx = t + it * 256;           // 4096 float4 = 128 rows x 32
      int row = idx >> 5, q = idx & 31;
      float4 v = *(const float4*)&W2[(size_t)(sp * 128 + row) * 128 + q * 4];
      u16x4 h, l; split4(v, &h, &l);
      *(u16x4*)&w2h[row][q * 4] = h;
      *(u16x4*)&w2l[row][q * 4] = l;
    }
    __syncthreads();
    f32x4 zz = {0.f, 0.f, 0.f, 0.f};
    f32x4 acc[4] = {zz, zz, zz, zz};
#pragma unroll
    for (int kk = 0; kk < 4; ++kk)
#pragma unroll
      for (int nt = 0; nt < 4; ++nt) {
        bf16x8 bhf = *(bf16x8*)&w2h[cq * 64 + nt * 16 + lr][kk * 32 + lk];
        bf16x8 blf = *(bf16x8*)&w2l[cq * 64 + nt * 16 + lr][kk * 32 + lk];
        acc[nt] = __builtin_amdgcn_mfma_f32_16x16x32_bf16(ah[kk], bhf, acc[nt], 0, 0, 0);
        acc[nt] = __builtin_amdgcn_mfma_f32_16x16x32_bf16(ah[kk], blf, acc[nt], 0, 0, 0);
        acc[nt] = __builtin_amdgcn_mfma_f32_16x16x32_bf16(al[kk], bhf, acc[nt], 0, 0, 0);
      }
#pragma unroll
    for (int nt = 0; nt < 4; ++nt) {
      float bias = b2[sp * 128 + cq * 64 + nt * 16 + lr];
#pragma unroll
      for (int r = 0; r < 4; ++r) m2x[nt][r] = fmaxf(m2x[nt][r], acc[nt][r] + bias);
    }
  }
#pragma unroll
  for (int nt = 0; nt < 4; ++nt)
#pragma unroll
    for (int r = 0; r < 4; ++r)
      m2f[rh * 16 + lq * 4 + r][cq * 64 + nt * 16 + lr] = m2x[nt][r];
  __syncthreads();

  // ---- phase 3: f32 [m1|m2] @ W3^T + b3, max over 8 ----
  {
    int row = t & 31, jp = t >> 5;
    const float* w3 = W3 + jp * 256;
    float acc = b3[jp];
    for (int f = 0; f < 128; f += 4) {
      float4 w = *(const float4*)&w3[f];
      acc += w.x * m1f[row][f] + w.y * m1f[row][f + 1] + w.z * m1f[row][f + 2] + w.w * m1f[row][f + 3];
    }
    for (int f = 0; f < 128; f += 4) {
      float4 w = *(const float4*)&w3[128 + f];
      acc += w.x * m2f[row][f] + w.y * m2f[row][f + 1] + w.z * m2f[row][f + 2] + w.w * m2f[row][f + 3];
    }
    sj[row][jp] = acc;
  }
  __syncthreads();
  if (t < 32) {
    float mx = sj[t][0];
#pragma unroll
    for (int j = 1; j < 8; ++j) mx = fmaxf(mx, sj[t][j]);
    outp[m0 + t] = mx;
  }
}

// =====================================================================
// slow fallback (tiny ws): one block per m, all f32 direct
// =====================================================================
__global__ void k_score_slow(
    const float* __restrict__ U,
    const float* __restrict__ We_a, const float* __restrict__ We_b,
    const float* __restrict__ W2_a, const float* __restrict__ b2_a,
    const float* __restrict__ W3_a, const float* __restrict__ b3_a,
    const float* __restrict__ W2_b, const float* __restrict__ b2_b,
    const float* __restrict__ W3_b, const float* __restrict__ b3_b,
    float* __restrict__ out_a, float* __restrict__ out_b,
    const float* __restrict__ ws) {
  __shared__ float u[256];
  __shared__ float m1s[128];
  __shared__ float m2v[1024];
  __shared__ float m2s[128];
  __shared__ float sjs[8];
  int t = threadIdx.x;
  int m = blockIdx.x;
  int suf = blockIdx.y;
  const float* We = suf ? We_b : We_a;
  const float* W2 = suf ? W2_b : W2_a;
  const float* b2 = suf ? b2_b : b2_a;
  const float* W3 = suf ? W3_b : W3_a;
  const float* b3 = suf ? b3_b : b3_a;
  float*     outp = suf ? out_b : out_a;
  float g0 = ws[WS_GS + suf * 2 + 0];
  float g1 = ws[WS_GS + suf * 2 + 1];
  const float* rt = ws + WS_RT + suf * 2048;

  u[t] = U[(size_t)m * 256 + t];
  __syncthreads();
  if (t < 128) {
    float mx[2] = {NEG_INF, NEG_INF};
    for (int k = 0; k < 2; ++k)
      for (int pp = 0; pp < 8; ++pp) {
        int e = k * 1024 + pp * 128 + t;
        const float* w = We + (size_t)e * 384;
        float acc = rt[e];
        for (int f = 0; f < 256; f += 4) {
          float4 wv = *(const float4*)&w[f];
          acc += wv.x * u[f] + wv.y * u[f + 1] + wv.z * u[f + 2] + wv.w * u[f + 3];
        }
        mx[k] = fmaxf(mx[k], acc);
      }
    m1s[t] = g0 * mx[0] + g1 * mx[1];
  }
  __syncthreads();
  for (int e = t; e < 1024; e += 256) {
    const float* w = W2 + (size_t)e * 128;
    float acc = b2[e];
    for (int f = 0; f < 128; f += 4) {
      float4 wv = *(const float4*)&w[f];
      acc += wv.x * m1s[f] + wv.y * m1s[f + 1] + wv.z * m1s[f + 2] + wv.w * m1s[f + 3];
    }
    m2v[e] = acc;
  }
  __syncthreads();
  if (t < 128) {
    float mx = NEG_INF;
    for (int pp = 0; pp < 8; ++pp) mx = fmaxf(mx, m2v[pp * 128 + t]);
    m2s[t] = mx;
  }
  __syncthreads();
  if (t < 8) {
    const float* w3 = W3 + t * 256;
    float acc = b3[t];
    for (int f = 0; f < 128; ++f) acc += w3[f] * m1s[f];
    for (int f = 0; f < 128; ++f) acc += w3[128 + f] * m2s[f];
    sjs[t] = acc;
  }
  __syncthreads();
  if (t == 0) {
    float mx = sjs[0];
    for (int j = 1; j < 8; ++j) mx = fmaxf(mx, sjs[j]);
    outp[m] = mx;
  }
}

// =====================================================================
extern "C" void kernel_launch(void* const* d_in, const int* in_sizes, int n_in,
                              void* d_out, int out_size, void* d_ws, size_t ws_size,
                              hipStream_t stream) {
  const float* U    = (const float*)d_in[0];
  const float* Wih  = (const float*)d_in[1];
  const float* Whh  = (const float*)d_in[2];
  const float* bih  = (const float*)d_in[3];
  const float* bhh  = (const float*)d_in[4];
  const float* Wr_s = (const float*)d_in[5];
  const float* br_s = (const float*)d_in[6];
  const float* Wg_s = (const float*)d_in[7];
  const float* bg_s = (const float*)d_in[8];
  const float* We_s = (const float*)d_in[9];
  const float* be_s = (const float*)d_in[10];
  const float* W2_s = (const float*)d_in[11];
  const float* b2_s = (const float*)d_in[12];
  const float* W3_s = (const float*)d_in[13];
  const float* b3_s = (const float*)d_in[14];
  const float* Wr_e = (const float*)d_in[15];
  const float* br_e = (const float*)d_in[16];
  const float* Wg_e = (const float*)d_in[17];
  const float* bg_e = (const float*)d_in[18];
  const float* We_e = (const float*)d_in[19];
  const float* be_e = (const float*)d_in[20];
  const float* W2_e = (const float*)d_in[21];
  const float* b2_e = (const float*)d_in[22];
  const float* W3_e = (const float*)d_in[23];
  const float* b3_e = (const float*)d_in[24];
  float* out = (float*)d_out;
  float* ws  = (float*)d_ws;

  int fast = (ws_size >= (size_t)WS_END * 4);

  k_init<<<1, 128, 0, stream>>>(ws);
  if (fast) {
    k_z0m<<<dim3(32, 8, 4), 256, 0, stream>>>(U, We_s, We_e, ws);
  }

  for (int step = 0; step < NSTEP; ++step) {
    k_state<<<1, 512, 0, stream>>>(U, Wih, Whh, bih, bhh,
                                   Wr_s, br_s, Wg_s, bg_s, We_s, be_s,
                                   Wr_e, br_e, Wg_e, bg_e, We_e, be_e,
                                   out, step, ws);

    float* out_s = out + (size_t)step * MM;
    float* out_e = out + (size_t)NSTEP * MM + (size_t)step * MM;

    if (fast) {
      k_score<<<dim3(128, 2), 256, 0, stream>>>(
          W2_s, b2_s, W3_s, b3_s,
          W2_e, b2_e, W3_e, b3_e,
          out_s, out_e, ws);
    } else {
      k_score_slow<<<dim3(MM, 2), 256, 0, stream>>>(
          U, We_s, We_e,
          W2_s, b2_s, W3_s, b3_s,
          W2_e, b2_e, W3_e, b3_e,
          out_s, out_e, ws);
    }
  }
}

// Round 4
// 376.128 us; speedup vs baseline: 2.9485x; 2.9485x over previous
//
#include <hip/hip_runtime.h>
#include <math.h>

// ---------------- problem constants ----------------
#define DD   128
#define MM   4096
#define NSTEP 4
#define NEG_INF (-3.4e38f)

// ---------------- ws float-offset layout ----------------
#define WS_H0   0          // h slots [2][128] -> 0..255
#define WS_C0   256        // c slots [2][128] -> 256..511
#define WS_G    512        // 512 gate preacts
#define WS_RS   1024       // 128
#define WS_RE   1152       // 128
#define WS_GS   1280       // 4: [gs0,gs1,ge0,ge1]
#define WS_SIEI 1284       // 2 ints
#define WS_RT   2048       // 4096: [suf][k*1024+e]
#define WS_Z0   8192       // f32 z0 [suf*2+k][4096][1024] = 16,777,216 floats
#define WS_END  (8192 + 16777216)   // 67,141,632 B

typedef __attribute__((ext_vector_type(8))) short bf16x8;
typedef __attribute__((ext_vector_type(4))) float f32x4;
typedef __attribute__((ext_vector_type(4))) unsigned short u16x4;

static __device__ __forceinline__ unsigned short f2b(float x) {
  unsigned u = __float_as_uint(x);
  unsigned r = (u + 0x7fffu + ((u >> 16) & 1u)) >> 16;   // RNE
  return (unsigned short)r;
}
static __device__ __forceinline__ float b2f(unsigned short h) {
  return __uint_as_float(((unsigned)h) << 16);
}
static __device__ __forceinline__ void split4(float4 v, u16x4* h, u16x4* l) {
  unsigned short h0 = f2b(v.x), h1 = f2b(v.y), h2 = f2b(v.z), h3 = f2b(v.w);
  u16x4 hh = {h0, h1, h2, h3};
  u16x4 ll = {f2b(v.x - b2f(h0)), f2b(v.y - b2f(h1)),
              f2b(v.z - b2f(h2)), f2b(v.w - b2f(h3))};
  *h = hh; *l = ll;
}
static __device__ __forceinline__ float sigm(float x) {
  return 1.f / (1.f + expf(-x));
}

// =====================================================================
// init: reset h/c slot 0 each launch (graph replays)
// =====================================================================
__global__ void k_init(float* __restrict__ ws) {
  int t = threadIdx.x;
  if (t < 128) { ws[WS_H0 + t] = 0.f; ws[WS_C0 + t] = 0.f; }
}

// =====================================================================
// Z0 split-bf16 MFMA GEMM (f32-grade):
// z0[z][m][e] = sum_{f<256} U[m][f] * We_z[e][f],  z = suf*2+k
// grid (32, 8, 4), 256 thr = 4 waves (2x2 of 64x64), BK=32
// =====================================================================
__global__ __launch_bounds__(256) void k_z0m(
    const float* __restrict__ U,
    const float* __restrict__ We_s, const float* __restrict__ We_e,
    float* __restrict__ ws) {
  __shared__ unsigned short Ah[128][40];
  __shared__ unsigned short Al[128][40];
  __shared__ unsigned short Bh[128][40];
  __shared__ unsigned short Bl[128][40];
  float* z0 = ws + WS_Z0;

  int t = threadIdx.x;
  int lane = t & 63, wid = t >> 6;
  int wm = wid >> 1, wn = wid & 1;
  int lr = lane & 15, lk = (lane >> 4) * 8, lq = lane >> 4;
  int m0 = blockIdx.x * 128, e0 = blockIdx.y * 128;
  int z = blockIdx.z;
  int suf = z >> 1, k = z & 1;
  const float* Wep = (suf ? We_e : We_s) + (size_t)k * 1024 * 384;

  f32x4 acc[4][4];
  f32x4 zz = {0.f, 0.f, 0.f, 0.f};
#pragma unroll
  for (int i = 0; i < 4; ++i)
#pragma unroll
    for (int n = 0; n < 4; ++n) acc[i][n] = zz;

  for (int kc = 0; kc < 8; ++kc) {
    int k0 = kc * 32;
    __syncthreads();
#pragma unroll
    for (int it = 0; it < 4; ++it) {
      int idx = t + it * 256;
      int row = idx >> 3, q = idx & 7;
      float4 va = *(const float4*)&U[(size_t)(m0 + row) * 256 + k0 + q * 4];
      u16x4 h, l; split4(va, &h, &l);
      *(u16x4*)&Ah[row][q * 4] = h;
      *(u16x4*)&Al[row][q * 4] = l;
      float4 vb = *(const float4*)&Wep[(size_t)(e0 + row) * 384 + k0 + q * 4];
      split4(vb, &h, &l);
      *(u16x4*)&Bh[row][q * 4] = h;
      *(u16x4*)&Bl[row][q * 4] = l;
    }
    __syncthreads();
    bf16x8 ah[4], al[4], bh[4], bl[4];
#pragma unroll
    for (int i = 0; i < 4; ++i) {
      ah[i] = *(bf16x8*)&Ah[wm * 64 + i * 16 + lr][lk];
      al[i] = *(bf16x8*)&Al[wm * 64 + i * 16 + lr][lk];
    }
#pragma unroll
    for (int n = 0; n < 4; ++n) {
      bh[n] = *(bf16x8*)&Bh[wn * 64 + n * 16 + lr][lk];
      bl[n] = *(bf16x8*)&Bl[wn * 64 + n * 16 + lr][lk];
    }
#pragma unroll
    for (int i = 0; i < 4; ++i)
#pragma unroll
      for (int n = 0; n < 4; ++n) {
        acc[i][n] = __builtin_amdgcn_mfma_f32_16x16x32_bf16(ah[i], bh[n], acc[i][n], 0, 0, 0);
        acc[i][n] = __builtin_amdgcn_mfma_f32_16x16x32_bf16(ah[i], bl[n], acc[i][n], 0, 0, 0);
        acc[i][n] = __builtin_amdgcn_mfma_f32_16x16x32_bf16(al[i], bh[n], acc[i][n], 0, 0, 0);
      }
  }

  float* C = z0 + (size_t)z * MM * 1024;
#pragma unroll
  for (int i = 0; i < 4; ++i)
#pragma unroll
    for (int n = 0; n < 4; ++n)
#pragma unroll
      for (int r = 0; r < 4; ++r) {
        int row = m0 + wm * 64 + i * 16 + lq * 4 + r;
        int col = e0 + wn * 64 + n * 16 + lr;
        C[(size_t)row * 1024 + col] = acc[i][n][r];
      }
}

// =====================================================================
// k_gates: per-block redundant argmax(prev scores) -> si/ei; then
// 16 gate rows per block: g[j] = Wih[j].x + Whh[j].h + bih + bhh.
// grid 32 x 256.
// =====================================================================
__global__ __launch_bounds__(256) void k_gates(
    const float* __restrict__ U,
    const float* __restrict__ Wih, const float* __restrict__ Whh,
    const float* __restrict__ bih, const float* __restrict__ bhh,
    const float* __restrict__ out, int step,
    float* __restrict__ ws) {
  __shared__ float ctx2[640];   // [us(256), ue(256), h(128)]
  __shared__ float rv[256];
  __shared__ int   ri[256];
  __shared__ int   sei[2];
  int t = threadIdx.x;
  int b = blockIdx.x;

  if (step > 0) {
    int half = t >> 7, l = t & 127;
    const float* arr = out + (size_t)half * (NSTEP * MM) + (size_t)(step - 1) * MM;
    float bv = NEG_INF; int bi = 0;
    for (int i = l; i < MM; i += 128) {
      float v = arr[i];
      if (v > bv) { bv = v; bi = i; }
    }
    rv[t] = bv; ri[t] = bi;
    __syncthreads();
    for (int s = 64; s > 0; s >>= 1) {
      if (l < s) {
        float v2 = rv[t + s]; int i2 = ri[t + s];
        if (v2 > rv[t] || (v2 == rv[t] && i2 < ri[t])) { rv[t] = v2; ri[t] = i2; }
      }
      __syncthreads();
    }
    if (l == 0) sei[half] = ri[t];
    __syncthreads();
  } else {
    if (t == 0) { sei[0] = 0; sei[1] = MM - 1; }
    __syncthreads();
  }
  int si = sei[0], ei = sei[1];
  if (b == 0 && t == 0) { ((int*)ws)[WS_SIEI] = si; ((int*)ws)[WS_SIEI + 1] = ei; }

  ctx2[t]       = U[(size_t)si * 256 + t];
  ctx2[256 + t] = U[(size_t)ei * 256 + t];
  if (t < 128) ctx2[512 + t] = ws[WS_H0 + (step & 1) * 128 + t];
  __syncthreads();

  int row = b * 16 + (t >> 4), sub = t & 15;
  const float* wih = Wih + (size_t)row * 512;
  const float* whh = Whh + (size_t)row * 128;
  float acc = 0.f;
  int e0 = sub * 40;
#pragma unroll
  for (int e = e0; e < e0 + 40; e += 4) {
    float4 w = (e < 512) ? *(const float4*)&wih[e] : *(const float4*)&whh[e - 512];
    acc += w.x * ctx2[e] + w.y * ctx2[e + 1] + w.z * ctx2[e + 2] + w.w * ctx2[e + 3];
  }
#pragma unroll
  for (int off = 8; off > 0; off >>= 1) acc += __shfl_down(acc, off, 16);
  if (sub == 0) ws[WS_G + row] = acc + bih[row] + bhh[row];
}

// =====================================================================
// k_r: every block redundantly computes h2/c2 from gates (double-buffered);
// blocks 0..15: 16 r-rows each (2 suffixes x 128); block 16: gate logits +
// softmax + h/c writeback.  grid 17 x 256.
// =====================================================================
__global__ __launch_bounds__(256) void k_r(
    const float* __restrict__ U,
    const float* __restrict__ Wr_s, const float* __restrict__ br_s,
    const float* __restrict__ Wg_s, const float* __restrict__ bg_s,
    const float* __restrict__ Wr_e, const float* __restrict__ br_e,
    const float* __restrict__ Wg_e, const float* __restrict__ bg_e,
    int step, float* __restrict__ ws) {
  __shared__ float ctxR[640];   // [h2(128), us(256), ue(256)]
  __shared__ float gl[512];
  __shared__ float logit[4];
  int t = threadIdx.x, b = blockIdx.x;
  int si = ((const int*)ws)[WS_SIEI], ei = ((const int*)ws)[WS_SIEI + 1];

  gl[t] = ws[WS_G + t];
  gl[256 + t] = ws[WS_G + 256 + t];
  ctxR[128 + t] = U[(size_t)si * 256 + t];
  ctxR[384 + t] = U[(size_t)ei * 256 + t];
  __syncthreads();
  if (t < 128) {
    float ig = sigm(gl[t]);
    float fg = sigm(gl[128 + t]);
    float gg = tanhf(gl[256 + t]);
    float og = sigm(gl[384 + t]);
    float cp = ws[WS_C0 + (step & 1) * 128 + t];
    float c2 = fg * cp + ig * gg;
    float h2 = og * tanhf(c2);
    ctxR[t] = h2;
    if (b == 16) {
      ws[WS_C0 + ((step + 1) & 1) * 128 + t] = c2;
      ws[WS_H0 + ((step + 1) & 1) * 128 + t] = h2;
    }
  }
  __syncthreads();

  if (b < 16) {
    int rr = b * 16 + (t >> 4), sub = t & 15;
    int suf = rr >> 7, i = rr & 127;
    const float* Wr = suf ? Wr_e : Wr_s;
    const float* br = suf ? br_e : br_s;
    const float* w = Wr + (size_t)i * 640;
    float acc = 0.f;
    int e0 = sub * 40;
#pragma unroll
    for (int e = e0; e < e0 + 40; e += 4) {
      float4 wv = *(const float4*)&w[e];
      acc += wv.x * ctxR[e] + wv.y * ctxR[e + 1] + wv.z * ctxR[e + 2] + wv.w * ctxR[e + 3];
    }
#pragma unroll
    for (int off = 8; off > 0; off >>= 1) acc += __shfl_down(acc, off, 16);
    if (sub == 0) ws[(suf ? WS_RE : WS_RS) + i] = tanhf(acc + br[i]);
  } else {
    if (t < 64) {
      int which = t >> 4, sub = t & 15;    // 0,1: s ; 2,3: e
      const float* Wg = (which < 2) ? Wg_s : Wg_e;
      const float* bg = (which < 2) ? bg_s : bg_e;
      int i = which & 1;
      const float* w = Wg + (size_t)i * 640;
      float acc = 0.f;
      int e0 = sub * 40;
#pragma unroll
      for (int e = e0; e < e0 + 40; e += 4) {
        float4 wv = *(const float4*)&w[e];
        acc += wv.x * ctxR[e] + wv.y * ctxR[e + 1] + wv.z * ctxR[e + 2] + wv.w * ctxR[e + 3];
      }
#pragma unroll
      for (int off = 8; off > 0; off >>= 1) acc += __shfl_down(acc, off, 16);
      if (sub == 0) logit[which] = acc + bg[i];
    }
    __syncthreads();
    if (t == 0) {
      float a = logit[0], bb = logit[1], mx = fmaxf(a, bb);
      float ea = expf(a - mx), eb = expf(bb - mx), s = ea + eb;
      ws[WS_GS + 0] = ea / s; ws[WS_GS + 1] = eb / s;
      a = logit[2]; bb = logit[3]; mx = fmaxf(a, bb);
      ea = expf(a - mx); eb = expf(bb - mx); s = ea + eb;
      ws[WS_GS + 2] = ea / s; ws[WS_GS + 3] = eb / s;
    }
  }
}

// =====================================================================
// k_rt: rterm[row] = be + We_tail[row] . r_suf.  grid 64 x 256 (64 rows/blk,
// 4 threads/row).
// =====================================================================
__global__ __launch_bounds__(256) void k_rt(
    const float* __restrict__ We_s, const float* __restrict__ be_s,
    const float* __restrict__ We_e, const float* __restrict__ be_e,
    float* __restrict__ ws) {
  __shared__ float rsh[256];
  int t = threadIdx.x, b = blockIdx.x;
  rsh[t] = ws[WS_RS + t];          // WS_RS(128) and WS_RE(128) are contiguous
  __syncthreads();
  int lrw = t >> 2, sub = t & 3;
  int row = b * 64 + lrw;          // 0..4095
  int suf = row >> 11, ke = row & 2047;
  const float* We = suf ? We_e : We_s;
  const float* be = suf ? be_e : be_s;
  const float* w = We + (size_t)ke * 384 + 256;
  const float* r = rsh + suf * 128;
  float acc = 0.f;
  int e0 = sub * 32;
#pragma unroll
  for (int e = e0; e < e0 + 32; e += 4) {
    float4 wv = *(const float4*)&w[e];
    acc += wv.x * r[e] + wv.y * r[e + 1] + wv.z * r[e + 2] + wv.w * r[e + 3];
  }
#pragma unroll
  for (int off = 2; off > 0; off >>= 1) acc += __shfl_down(acc, off, 4);
  if (sub == 0) ws[WS_RT + row] = acc + be[ke];
}

// =====================================================================
// score: ph1 f32 maxout+mix -> m1f; ph2 split-bf16 MFMA m1@W2^T maxout -> m2f;
// ph3 f32 [m1|m2]@W3^T max -> scores.  grid (128, 2), 256 thr.
// =====================================================================
__global__ __launch_bounds__(256) void k_score(
    const float* __restrict__ W2_a, const float* __restrict__ b2_a,
    const float* __restrict__ W3_a, const float* __restrict__ b3_a,
    const float* __restrict__ W2_b, const float* __restrict__ b2_b,
    const float* __restrict__ W3_b, const float* __restrict__ b3_b,
    float* __restrict__ out_a, float* __restrict__ out_b,
    float* __restrict__ ws) {
  __shared__ float rtm[2048];
  __shared__ float m1f[32][132];
  __shared__ unsigned short w2h[128][136];
  __shared__ unsigned short w2l[128][136];
  __shared__ float m2f[32][132];
  __shared__ float sj[32][8];

  const float* z0 = ws + WS_Z0;
  int t = threadIdx.x;
  int suf = blockIdx.y;
  int m0 = blockIdx.x * 32;
  const float* W2 = suf ? W2_b : W2_a;
  const float* b2 = suf ? b2_b : b2_a;
  const float* W3 = suf ? W3_b : W3_a;
  const float* b3 = suf ? b3_b : b3_a;
  float*     outp = suf ? out_b : out_a;
  float g0 = ws[WS_GS + suf * 2 + 0];
  float g1 = ws[WS_GS + suf * 2 + 1];

  for (int l = t; l < 2048; l += 256) rtm[l] = ws[WS_RT + suf * 2048 + l];
  __syncthreads();

  // ---- phase 1: f32 maxout over p, mixture over k -> m1f ----
  {
    int cg = t & 31, rgi = t >> 5;
    int c4 = cg * 4;
    const float* z00 = z0 + (size_t)(suf * 2 + 0) * MM * 1024;
    const float* z01 = z0 + (size_t)(suf * 2 + 1) * MM * 1024;
#pragma unroll
    for (int it = 0; it < 4; ++it) {
      int row = it * 8 + rgi;
      size_t mb = (size_t)(m0 + row) * 1024;
      float4 mx0 = {NEG_INF, NEG_INF, NEG_INF, NEG_INF};
      float4 mx1 = mx0;
#pragma unroll
      for (int pp = 0; pp < 8; ++pp) {
        float4 v0 = *(const float4*)&z00[mb + pp * 128 + c4];
        float4 r0 = *(const float4*)&rtm[pp * 128 + c4];
        mx0.x = fmaxf(mx0.x, v0.x + r0.x); mx0.y = fmaxf(mx0.y, v0.y + r0.y);
        mx0.z = fmaxf(mx0.z, v0.z + r0.z); mx0.w = fmaxf(mx0.w, v0.w + r0.w);
        float4 v1 = *(const float4*)&z01[mb + pp * 128 + c4];
        float4 r1 = *(const float4*)&rtm[1024 + pp * 128 + c4];
        mx1.x = fmaxf(mx1.x, v1.x + r1.x); mx1.y = fmaxf(mx1.y, v1.y + r1.y);
        mx1.z = fmaxf(mx1.z, v1.z + r1.z); mx1.w = fmaxf(mx1.w, v1.w + r1.w);
      }
      float4 m1v = {g0 * mx0.x + g1 * mx1.x, g0 * mx0.y + g1 * mx1.y,
                    g0 * mx0.z + g1 * mx1.z, g0 * mx0.w + g1 * mx1.w};
      *(float4*)&m1f[row][c4] = m1v;
    }
  }
  __syncthreads();

  // ---- per-wave A-fragments (split m1 to hi/lo in registers) ----
  int lane = t & 63, wid = t >> 6;
  int rh = wid & 1, cq = wid >> 1;
  int lr = lane & 15, lk = (lane >> 4) * 8, lq = lane >> 4;
  bf16x8 ah[4], al[4];
#pragma unroll
  for (int kk = 0; kk < 4; ++kk) {
    float4 x0 = *(const float4*)&m1f[rh * 16 + lr][kk * 32 + lk];
    float4 x1 = *(const float4*)&m1f[rh * 16 + lr][kk * 32 + lk + 4];
    u16x4 h0, l0, h1, l1;
    split4(x0, &h0, &l0); split4(x1, &h1, &l1);
    bf16x8 a, b;
#pragma unroll
    for (int j = 0; j < 4; ++j) { a[j] = (short)h0[j]; a[4 + j] = (short)h1[j]; }
#pragma unroll
    for (int j = 0; j < 4; ++j) { b[j] = (short)l0[j]; b[4 + j] = (short)l1[j]; }
    ah[kk] = a; al[kk] = b;
  }

  // ---- phase 2: split-bf16 MFMA, maxout over sp ----
  float m2x[4][4];
#pragma unroll
  for (int nt = 0; nt < 4; ++nt)
#pragma unroll
    for (int r = 0; r < 4; ++r) m2x[nt][r] = NEG_INF;

  for (int sp = 0; sp < 8; ++sp) {
    __syncthreads();
#pragma unroll
    for (int it = 0; it < 16; ++it) {
      int idx = t + it * 256;
      int row = idx >> 5, q = idx & 31;
      float4 v = *(const float4*)&W2[(size_t)(sp * 128 + row) * 128 + q * 4];
      u16x4 h, l; split4(v, &h, &l);
      *(u16x4*)&w2h[row][q * 4] = h;
      *(u16x4*)&w2l[row][q * 4] = l;
    }
    __syncthreads();
    f32x4 zz = {0.f, 0.f, 0.f, 0.f};
    f32x4 acc[4] = {zz, zz, zz, zz};
#pragma unroll
    for (int kk = 0; kk < 4; ++kk)
#pragma unroll
      for (int nt = 0; nt < 4; ++nt) {
        bf16x8 bhf = *(bf16x8*)&w2h[cq * 64 + nt * 16 + lr][kk * 32 + lk];
        bf16x8 blf = *(bf16x8*)&w2l[cq * 64 + nt * 16 + lr][kk * 32 + lk];
        acc[nt] = __builtin_amdgcn_mfma_f32_16x16x32_bf16(ah[kk], bhf, acc[nt], 0, 0, 0);
        acc[nt] = __builtin_amdgcn_mfma_f32_16x16x32_bf16(ah[kk], blf, acc[nt], 0, 0, 0);
        acc[nt] = __builtin_amdgcn_mfma_f32_16x16x32_bf16(al[kk], bhf, acc[nt], 0, 0, 0);
      }
#pragma unroll
    for (int nt = 0; nt < 4; ++nt) {
      float bias = b2[sp * 128 + cq * 64 + nt * 16 + lr];
#pragma unroll
      for (int r = 0; r < 4; ++r) m2x[nt][r] = fmaxf(m2x[nt][r], acc[nt][r] + bias);
    }
  }
#pragma unroll
  for (int nt = 0; nt < 4; ++nt)
#pragma unroll
    for (int r = 0; r < 4; ++r)
      m2f[rh * 16 + lq * 4 + r][cq * 64 + nt * 16 + lr] = m2x[nt][r];
  __syncthreads();

  // ---- phase 3: f32 [m1|m2] @ W3^T + b3, max over 8 ----
  {
    int row = t & 31, jp = t >> 5;
    const float* w3 = W3 + jp * 256;
    float acc = b3[jp];
    for (int f = 0; f < 128; f += 4) {
      float4 w = *(const float4*)&w3[f];
      acc += w.x * m1f[row][f] + w.y * m1f[row][f + 1] + w.z * m1f[row][f + 2] + w.w * m1f[row][f + 3];
    }
    for (int f = 0; f < 128; f += 4) {
      float4 w = *(const float4*)&w3[128 + f];
      acc += w.x * m2f[row][f] + w.y * m2f[row][f + 1] + w.z * m2f[row][f + 2] + w.w * m2f[row][f + 3];
    }
    sj[row][jp] = acc;
  }
  __syncthreads();
  if (t < 32) {
    float mx = sj[t][0];
#pragma unroll
    for (int j = 1; j < 8; ++j) mx = fmaxf(mx, sj[t][j]);
    outp[m0 + t] = mx;
  }
}

// =====================================================================
// slow fallback (tiny ws): one block per m, all f32 direct
// =====================================================================
__global__ void k_score_slow(
    const float* __restrict__ U,
    const float* __restrict__ We_a, const float* __restrict__ We_b,
    const float* __restrict__ W2_a, const float* __restrict__ b2_a,
    const float* __restrict__ W3_a, const float* __restrict__ b3_a,
    const float* __restrict__ W2_b, const float* __restrict__ b2_b,
    const float* __restrict__ W3_b, const float* __restrict__ b3_b,
    float* __restrict__ out_a, float* __restrict__ out_b,
    const float* __restrict__ ws) {
  __shared__ float u[256];
  __shared__ float m1s[128];
  __shared__ float m2v[1024];
  __shared__ float m2s[128];
  __shared__ float sjs[8];
  int t = threadIdx.x;
  int m = blockIdx.x;
  int suf = blockIdx.y;
  const float* We = suf ? We_b : We_a;
  const float* W2 = suf ? W2_b : W2_a;
  const float* b2 = suf ? b2_b : b2_a;
  const float* W3 = suf ? W3_b : W3_a;
  const float* b3 = suf ? b3_b : b3_a;
  float*     outp = suf ? out_b : out_a;
  float g0 = ws[WS_GS + suf * 2 + 0];
  float g1 = ws[WS_GS + suf * 2 + 1];
  const float* rt = ws + WS_RT + suf * 2048;

  u[t] = U[(size_t)m * 256 + t];
  __syncthreads();
  if (t < 128) {
    float mx[2] = {NEG_INF, NEG_INF};
    for (int k = 0; k < 2; ++k)
      for (int pp = 0; pp < 8; ++pp) {
        int e = k * 1024 + pp * 128 + t;
        const float* w = We + (size_t)e * 384;
        float acc = rt[e];
        for (int f = 0; f < 256; f += 4) {
          float4 wv = *(const float4*)&w[f];
          acc += wv.x * u[f] + wv.y * u[f + 1] + wv.z * u[f + 2] + wv.w * u[f + 3];
        }
        mx[k] = fmaxf(mx[k], acc);
      }
    m1s[t] = g0 * mx[0] + g1 * mx[1];
  }
  __syncthreads();
  for (int e = t; e < 1024; e += 256) {
    const float* w = W2 + (size_t)e * 128;
    float acc = b2[e];
    for (int f = 0; f < 128; f += 4) {
      float4 wv = *(const float4*)&w[f];
      acc += wv.x * m1s[f] + wv.y * m1s[f + 1] + wv.z * m1s[f + 2] + wv.w * m1s[f + 3];
    }
    m2v[e] = acc;
  }
  __syncthreads();
  if (t < 128) {
    float mx = NEG_INF;
    for (int pp = 0; pp < 8; ++pp) mx = fmaxf(mx, m2v[pp * 128 + t]);
    m2s[t] = mx;
  }
  __syncthreads();
  if (t < 8) {
    const float* w3 = W3 + t * 256;
    float acc = b3[t];
    for (int f = 0; f < 128; ++f) acc += w3[f] * m1s[f];
    for (int f = 0; f < 128; ++f) acc += w3[128 + f] * m2s[f];
    sjs[t] = acc;
  }
  __syncthreads();
  if (t == 0) {
    float mx = sjs[0];
    for (int j = 1; j < 8; ++j) mx = fmaxf(mx, sjs[j]);
    outp[m] = mx;
  }
}

// =====================================================================
extern "C" void kernel_launch(void* const* d_in, const int* in_sizes, int n_in,
                              void* d_out, int out_size, void* d_ws, size_t ws_size,
                              hipStream_t stream) {
  const float* U    = (const float*)d_in[0];
  const float* Wih  = (const float*)d_in[1];
  const float* Whh  = (const float*)d_in[2];
  const float* bih  = (const float*)d_in[3];
  const float* bhh  = (const float*)d_in[4];
  const float* Wr_s = (const float*)d_in[5];
  const float* br_s = (const float*)d_in[6];
  const float* Wg_s = (const float*)d_in[7];
  const float* bg_s = (const float*)d_in[8];
  const float* We_s = (const float*)d_in[9];
  const float* be_s = (const float*)d_in[10];
  const float* W2_s = (const float*)d_in[11];
  const float* b2_s = (const float*)d_in[12];
  const float* W3_s = (const float*)d_in[13];
  const float* b3_s = (const float*)d_in[14];
  const float* Wr_e = (const float*)d_in[15];
  const float* br_e = (const float*)d_in[16];
  const float* Wg_e = (const float*)d_in[17];
  const float* bg_e = (const float*)d_in[18];
  const float* We_e = (const float*)d_in[19];
  const float* be_e = (const float*)d_in[20];
  const float* W2_e = (const float*)d_in[21];
  const float* b2_e = (const float*)d_in[22];
  const float* W3_e = (const float*)d_in[23];
  const float* b3_e = (const float*)d_in[24];
  float* out = (float*)d_out;
  float* ws  = (float*)d_ws;

  int fast = (ws_size >= (size_t)WS_END * 4);

  k_init<<<1, 128, 0, stream>>>(ws);
  if (fast) {
    k_z0m<<<dim3(32, 8, 4), 256, 0, stream>>>(U, We_s, We_e, ws);
  }

  for (int step = 0; step < NSTEP; ++step) {
    k_gates<<<32, 256, 0, stream>>>(U, Wih, Whh, bih, bhh, out, step, ws);
    k_r<<<17, 256, 0, stream>>>(U, Wr_s, br_s, Wg_s, bg_s,
                                Wr_e, br_e, Wg_e, bg_e, step, ws);
    k_rt<<<64, 256, 0, stream>>>(We_s, be_s, We_e, be_e, ws);

    float* out_s = out + (size_t)step * MM;
    float* out_e = out + (size_t)NSTEP * MM + (size_t)step * MM;

    if (fast) {
      k_score<<<dim3(128, 2), 256, 0, stream>>>(
          W2_s, b2_s, W3_s, b3_s,
          W2_e, b2_e, W3_e, b3_e,
          out_s, out_e, ws);
    } else {
      k_score_slow<<<dim3(MM, 2), 256, 0, stream>>>(
          U, We_s, We_e,
          W2_s, b2_s, W3_s, b3_s,
          W2_e, b2_e, W3_e, b3_e,
          out_s, out_e, ws);
    }
  }
}